// Round 1
// baseline (3236.266 us; speedup 1.0000x reference)
//
#include <hip/hip_runtime.h>
#include <math.h>

// ---------------------------------------------------------------------------
// Problem constants
// ---------------------------------------------------------------------------
#define N_SEQ   896
#define DH      3072
#define NCTX    64
#define JLEN    127
#define DC      1024
#define HEADS   8
#define DHEAD   64
#define INNER   512   // HEADS*DHEAD

// workspace float offsets
#define OFF_EMU    0LL
#define OFF_ERSTD  (OFF_EMU   + N_SEQ)
#define OFF_EDOT   (OFF_ERSTD + N_SEQ)
#define OFF_CMU    (OFF_EDOT  + N_SEQ)
#define OFF_CRSTD  (OFF_CMU   + NCTX*JLEN)
#define OFF_Q      (OFF_CRSTD + NCTX*JLEN)                 // 896*512
#define OFF_KALL   (OFF_Q     + (long long)N_SEQ*INNER)    // 64*128*512
#define OFF_VALL   (OFF_KALL  + (long long)NCTX*128*INNER) // 64*127*512
#define OFF_VP     (OFF_VALL  + (long long)NCTX*JLEN*INNER)// 64*8*128
#define OFF_WOP    (OFF_VP    + NCTX*HEADS*128)
#define OFF_BOP    (OFF_WOP   + INNER)
#define OFF_SBUF   (OFF_BOP   + 16)                        // 64*8*896

// ---------------------------------------------------------------------------
// K1/K2: per-row layernorm stats (+ optional dot with Wp for embeddings)
// ---------------------------------------------------------------------------
__global__ void row_stats_kernel(const float* __restrict__ X, int K,
                                 const float* __restrict__ wp,
                                 float* __restrict__ mu, float* __restrict__ rstd,
                                 float* __restrict__ dotout) {
    int row = blockIdx.x;
    const float* x = X + (long long)row * K;
    float s = 0.f, ss = 0.f, dp = 0.f;
    for (int k = threadIdx.x; k < K; k += blockDim.x) {
        float v = x[k];
        s += v; ss += v * v;
        if (wp) dp += v * wp[k];
    }
    for (int o = 32; o > 0; o >>= 1) {
        s  += __shfl_down(s,  o);
        ss += __shfl_down(ss, o);
        dp += __shfl_down(dp, o);
    }
    __shared__ float red[3][4];
    int lane = threadIdx.x & 63, w = threadIdx.x >> 6;
    if (lane == 0) { red[0][w] = s; red[1][w] = ss; red[2][w] = dp; }
    __syncthreads();
    if (threadIdx.x == 0) {
        float S = 0.f, SS = 0.f, DP = 0.f;
        int nw = blockDim.x >> 6;
        for (int i = 0; i < nw; ++i) { S += red[0][i]; SS += red[1][i]; DP += red[2][i]; }
        float m   = S / K;
        float var = SS / K - m * m;
        mu[row]   = m;
        rstd[row] = rsqrtf(var + 1e-5f);
        if (dotout) dotout[row] = DP;
    }
}

// ---------------------------------------------------------------------------
// K3/K4: tiled fp32 GEMM with layernorm fused into the A-tile load.
// mode 0: C[r*N+col] = acc      (q projection)
// mode 1: kv scatter: col<512 -> k_all[c][1+j][col], col>=512 -> v_all (r= c*127+j)
// ---------------------------------------------------------------------------
#define BM 64
#define BN 64
#define BKK 16

__global__ __launch_bounds__(256)
void gemm_ln_kernel(const float* __restrict__ X, const float* __restrict__ mu,
                    const float* __restrict__ rstd, const float* __restrict__ gamma,
                    const float* __restrict__ beta, const float* __restrict__ B,
                    float* __restrict__ C, int M, int N, int K, int mode,
                    float* __restrict__ kout, float* __restrict__ vout) {
    __shared__ float As[BKK][BM + 4];
    __shared__ float Bs[BKK][BN + 4];
    int tid = threadIdx.x;
    int tx = tid & 15, ty = tid >> 4;
    int bm = blockIdx.x, bn = blockIdx.y;
    float acc[4][4] = {};
    for (int kt = 0; kt < K; kt += BKK) {
        #pragma unroll
        for (int e = 0; e < (BM * BKK) / 256; ++e) {
            int idx = tid + e * 256;
            int kl = idx & 15, m = idx >> 4;
            int gr = bm * BM + m, gk = kt + kl;
            float v = X[(long long)gr * K + gk];
            As[kl][m] = (v - mu[gr]) * rstd[gr] * gamma[gk] + beta[gk];
        }
        #pragma unroll
        for (int e = 0; e < (BKK * BN) / 256; ++e) {
            int idx = tid + e * 256;
            int nl = idx & 63, kl = idx >> 6;
            Bs[kl][nl] = B[(long long)(kt + kl) * N + bn * BN + nl];
        }
        __syncthreads();
        #pragma unroll
        for (int kk = 0; kk < BKK; ++kk) {
            float4 a4 = *(const float4*)&As[kk][ty * 4];
            float4 b4 = *(const float4*)&Bs[kk][tx * 4];
            float a[4] = {a4.x, a4.y, a4.z, a4.w};
            float b[4] = {b4.x, b4.y, b4.z, b4.w};
            #pragma unroll
            for (int i = 0; i < 4; ++i)
                #pragma unroll
                for (int j = 0; j < 4; ++j)
                    acc[i][j] += a[i] * b[j];
        }
        __syncthreads();
    }
    #pragma unroll
    for (int i = 0; i < 4; ++i) {
        int gr = bm * BM + ty * 4 + i;
        #pragma unroll
        for (int j = 0; j < 4; ++j) {
            int gc = bn * BN + tx * 4 + j;
            float v = acc[i][j];
            if (mode == 0) {
                C[(long long)gr * N + gc] = v;
            } else {
                int cc = gr / JLEN, jj = gr % JLEN;
                if (gc < INNER) kout[((long long)(cc * 128) + jj + 1) * INNER + gc] = v;
                else            vout[(long long)gr * INNER + (gc - INNER)] = v;
            }
        }
    }
}

// ---------------------------------------------------------------------------
// K5: wop = Wo @ Wp (512), bop = bo . Wp
// ---------------------------------------------------------------------------
__global__ void wop_kernel(const float* __restrict__ Wo, const float* __restrict__ bo,
                           const float* __restrict__ Wp, float* __restrict__ wop,
                           float* __restrict__ bop) {
    int r = blockIdx.x;  // 0..512; 512 -> bop
    const float* src = (r < INNER) ? (Wo + (long long)r * DH) : bo;
    float s = 0.f;
    for (int k = threadIdx.x; k < DH; k += blockDim.x) s += src[k] * Wp[k];
    for (int o = 32; o > 0; o >>= 1) s += __shfl_down(s, o);
    __shared__ float red[4];
    int lane = threadIdx.x & 63, w = threadIdx.x >> 6;
    if (lane == 0) red[w] = s;
    __syncthreads();
    if (threadIdx.x == 0) {
        float S = red[0] + red[1] + red[2] + red[3];
        if (r < INNER) wop[r] = S; else *bop = S;
    }
}

// ---------------------------------------------------------------------------
// K6: per-context prep: fill k_all[c][0] = null_k, vp[c][h][j] = v . wop_h
// ---------------------------------------------------------------------------
__global__ void vp_prep_kernel(const float* __restrict__ v_all,
                               const float* __restrict__ null_v,
                               const float* __restrict__ null_k,
                               const float* __restrict__ wop,
                               float* __restrict__ vp, float* __restrict__ k_all) {
    int c = blockIdx.x;
    for (int d = threadIdx.x; d < INNER; d += blockDim.x)
        k_all[(long long)(c * 128) * INNER + d] = null_k[d];
    for (int t = threadIdx.x; t < HEADS * 128; t += blockDim.x) {
        int h = t >> 7, j = t & 127;
        const float* vsrc = (j == 0)
            ? (null_v + h * DHEAD)
            : (v_all + ((long long)(c * JLEN + j - 1)) * INNER + h * DHEAD);
        const float* w = wop + h * DHEAD;
        float s = 0.f;
        #pragma unroll 8
        for (int d = 0; d < DHEAD; ++d) s += vsrc[d] * w[d];
        vp[(c * HEADS + h) * 128 + j] = s;
    }
}

// ---------------------------------------------------------------------------
// K7: attention: per (ntile, h, c): sim = q_tile @ k^T, mask, softmax, dot vp
// writes s_buf[c][h][n]
// ---------------------------------------------------------------------------
__global__ __launch_bounds__(256)
void attn_kernel(const float* __restrict__ q, const float* __restrict__ k_all,
                 const float* __restrict__ vp, const int* __restrict__ mask,
                 float* __restrict__ s_buf) {
    int ntile = blockIdx.x, h = blockIdx.y, c = blockIdx.z;
    int n0 = ntile * 64;
    __shared__ float qs[64][68];
    __shared__ float ks[128][68];
    __shared__ float vps[128];
    __shared__ float msk[128];
    int tid = threadIdx.x;
    #pragma unroll
    for (int e = 0; e < 4; ++e) {   // 64 rows x 16 float4
        int idx = tid + e * 256;
        int r = idx >> 4, c4 = (idx & 15) * 4;
        float4 v = *(const float4*)&q[(long long)(n0 + r) * INNER + h * DHEAD + c4];
        *(float4*)&qs[r][c4] = v;
    }
    #pragma unroll
    for (int e = 0; e < 8; ++e) {   // 128 rows x 16 float4
        int idx = tid + e * 256;
        int r = idx >> 4, c4 = (idx & 15) * 4;
        float4 v = *(const float4*)&k_all[(long long)(c * 128 + r) * INNER + h * DHEAD + c4];
        *(float4*)&ks[r][c4] = v;
    }
    if (tid < 128) {
        vps[tid] = vp[(c * HEADS + h) * 128 + tid];
        msk[tid] = (tid == 0) ? 1.f : (mask[tid - 1] ? 1.f : 0.f);
    }
    __syncthreads();
    int tx = tid & 15, ty = tid >> 4;
    float acc[4][8] = {};
    #pragma unroll
    for (int d = 0; d < DHEAD; d += 4) {
        float4 q4[4]; float4 k4[8];
        #pragma unroll
        for (int i = 0; i < 4; ++i) q4[i] = *(const float4*)&qs[ty * 4 + i][d];
        #pragma unroll
        for (int j = 0; j < 8; ++j) k4[j] = *(const float4*)&ks[tx * 8 + j][d];
        #pragma unroll
        for (int i = 0; i < 4; ++i)
            #pragma unroll
            for (int j = 0; j < 8; ++j)
                acc[i][j] += q4[i].x * k4[j].x + q4[i].y * k4[j].y
                           + q4[i].z * k4[j].z + q4[i].w * k4[j].w;
    }
    const float scale = 0.125f;
    #pragma unroll
    for (int j = 0; j < 8; ++j) {
        float mv = msk[tx * 8 + j];
        #pragma unroll
        for (int i = 0; i < 4; ++i)
            acc[i][j] = (mv > 0.f) ? acc[i][j] * scale : -3.402823466e38f;
    }
    #pragma unroll
    for (int i = 0; i < 4; ++i) {
        float m = -3.402823466e38f;
        #pragma unroll
        for (int j = 0; j < 8; ++j) m = fmaxf(m, acc[i][j]);
        for (int o = 1; o < 16; o <<= 1) m = fmaxf(m, __shfl_xor(m, o, 16));
        float l = 0.f, p = 0.f;
        #pragma unroll
        for (int j = 0; j < 8; ++j) {
            float e = __expf(acc[i][j] - m);
            l += e; p += e * vps[tx * 8 + j];
        }
        for (int o = 1; o < 16; o <<= 1) { l += __shfl_xor(l, o, 16); p += __shfl_xor(p, o, 16); }
        if (tx == 0) s_buf[((long long)(c * HEADS + h)) * N_SEQ + n0 + ty * 4 + i] = p / l;
    }
}

// ---------------------------------------------------------------------------
// K8: final: pred[n,c] = softplus(e_dot[n] + sum_h s[c,h,n] + bop + bp)
// ---------------------------------------------------------------------------
__global__ void final_kernel(const float* __restrict__ s_buf,
                             const float* __restrict__ e_dot,
                             const float* __restrict__ bop,
                             const float* __restrict__ bp,
                             float* __restrict__ out) {
    int t = blockIdx.x * blockDim.x + threadIdx.x;
    if (t >= N_SEQ * NCTX) return;
    int n = t >> 6, c = t & 63;
    float s = 0.f;
    #pragma unroll
    for (int h = 0; h < HEADS; ++h) s += s_buf[((long long)(c * HEADS + h)) * N_SEQ + n];
    float x = e_dot[n] + s + *bop + *bp;
    out[t] = fmaxf(x, 0.f) + log1pf(__expf(-fabsf(x)));
}

// ---------------------------------------------------------------------------
extern "C" void kernel_launch(void* const* d_in, const int* in_sizes, int n_in,
                              void* d_out, int out_size, void* d_ws, size_t ws_size,
                              hipStream_t stream) {
    const float* emb   = (const float*)d_in[0];
    const float* ctx   = (const float*)d_in[1];
    const int*   cmask = (const int*)  d_in[2];
    const float* qg    = (const float*)d_in[3];
    const float* qb    = (const float*)d_in[4];
    const float* kvg   = (const float*)d_in[5];
    const float* kvb   = (const float*)d_in[6];
    const float* Wq    = (const float*)d_in[7];
    const float* Wkv   = (const float*)d_in[8];
    const float* nullk = (const float*)d_in[9];
    const float* nullv = (const float*)d_in[10];
    const float* Wo    = (const float*)d_in[11];
    const float* bo    = (const float*)d_in[12];
    const float* Wp    = (const float*)d_in[13];
    const float* bp    = (const float*)d_in[14];
    float* out  = (float*)d_out;
    float* ws_f = (float*)d_ws;

    float* EMU   = ws_f + OFF_EMU;
    float* ERSTD = ws_f + OFF_ERSTD;
    float* EDOT  = ws_f + OFF_EDOT;
    float* CMU   = ws_f + OFF_CMU;
    float* CRSTD = ws_f + OFF_CRSTD;
    float* QBUF  = ws_f + OFF_Q;
    float* KALL  = ws_f + OFF_KALL;
    float* VALL  = ws_f + OFF_VALL;
    float* VP    = ws_f + OFF_VP;
    float* WOP   = ws_f + OFF_WOP;
    float* BOP   = ws_f + OFF_BOP;
    float* SBUF  = ws_f + OFF_SBUF;

    row_stats_kernel<<<N_SEQ, 256, 0, stream>>>(emb, DH, Wp, EMU, ERSTD, EDOT);
    row_stats_kernel<<<NCTX * JLEN, 256, 0, stream>>>(ctx, DC, nullptr, CMU, CRSTD, nullptr);
    gemm_ln_kernel<<<dim3(N_SEQ / BM, INNER / BN), 256, 0, stream>>>(
        emb, EMU, ERSTD, qg, qb, Wq, QBUF, N_SEQ, INNER, DH, 0, nullptr, nullptr);
    gemm_ln_kernel<<<dim3((NCTX * JLEN) / BM, (2 * INNER) / BN), 256, 0, stream>>>(
        ctx, CMU, CRSTD, kvg, kvb, Wkv, nullptr, NCTX * JLEN, 2 * INNER, DC, 1, KALL, VALL);
    wop_kernel<<<INNER + 1, 256, 0, stream>>>(Wo, bo, Wp, WOP, BOP);
    vp_prep_kernel<<<NCTX, 256, 0, stream>>>(VALL, nullv, nullk, WOP, VP, KALL);
    attn_kernel<<<dim3(N_SEQ / 64, HEADS, NCTX), 256, 0, stream>>>(QBUF, KALL, VP, cmask, SBUF);
    final_kernel<<<(N_SEQ * NCTX + 255) / 256, 256, 0, stream>>>(SBUF, EDOT, BOP, bp, out);
}

// Round 2
// 742.913 us; speedup vs baseline: 4.3562x; 4.3562x over previous
//
#include <hip/hip_runtime.h>
#include <math.h>

// ---------------------------------------------------------------------------
// Problem constants
// ---------------------------------------------------------------------------
#define N_SEQ   896
#define DH      3072
#define NCTX    64
#define JLEN    127
#define DC      1024
#define HEADS   8
#define DHEAD   64
#define INNER   512   // HEADS*DHEAD

typedef __bf16 bf16x8 __attribute__((ext_vector_type(8)));
typedef float  f32x4  __attribute__((ext_vector_type(4)));

// workspace float offsets
#define OFF_EMU    0LL
#define OFF_ERSTD  (OFF_EMU   + N_SEQ)
#define OFF_EDOT   (OFF_ERSTD + N_SEQ)
#define OFF_CMU    (OFF_EDOT  + N_SEQ)
#define OFF_CRSTD  (OFF_CMU   + NCTX*JLEN)
#define OFF_QBF    (OFF_CRSTD + NCTX*JLEN)                   // 896*512 bf16 = 229376 f
#define OFF_KBF    (OFF_QBF   + (long long)N_SEQ*INNER/2)    // 64*128*512 bf16 = 2097152 f
#define OFF_VALL   (OFF_KBF   + (long long)NCTX*128*INNER/2) // 64*127*512 f
#define OFF_VP     (OFF_VALL  + (long long)NCTX*JLEN*INNER)  // 64*8*128
#define OFF_WOP    (OFF_VP    + NCTX*HEADS*128)
#define OFF_BOP    (OFF_WOP   + INNER)
#define OFF_SBUF   (OFF_BOP   + 16)                          // 64*8*896

// ---------------------------------------------------------------------------
// K1/K2: per-row layernorm stats (+ optional dot with Wp for embeddings)
// ---------------------------------------------------------------------------
__global__ void row_stats_kernel(const float* __restrict__ X, int K,
                                 const float* __restrict__ wp,
                                 float* __restrict__ mu, float* __restrict__ rstd,
                                 float* __restrict__ dotout) {
    int row = blockIdx.x;
    const float* x = X + (long long)row * K;
    float s = 0.f, ss = 0.f, dp = 0.f;
    for (int k = threadIdx.x; k < K; k += blockDim.x) {
        float v = x[k];
        s += v; ss += v * v;
        if (wp) dp += v * wp[k];
    }
    for (int o = 32; o > 0; o >>= 1) {
        s  += __shfl_down(s,  o);
        ss += __shfl_down(ss, o);
        dp += __shfl_down(dp, o);
    }
    __shared__ float red[3][4];
    int lane = threadIdx.x & 63, w = threadIdx.x >> 6;
    if (lane == 0) { red[0][w] = s; red[1][w] = ss; red[2][w] = dp; }
    __syncthreads();
    if (threadIdx.x == 0) {
        float S = 0.f, SS = 0.f, DP = 0.f;
        int nw = blockDim.x >> 6;
        for (int i = 0; i < nw; ++i) { S += red[0][i]; SS += red[1][i]; DP += red[2][i]; }
        float m   = S / K;
        float var = SS / K - m * m;
        mu[row]   = m;
        rstd[row] = rsqrtf(var + 1e-5f);
        if (dotout) dotout[row] = DP;
    }
}

// ---------------------------------------------------------------------------
// K3/K4: tiled fp32 GEMM with layernorm fused into the A-tile load.
// mode 0: q projection -> bf16 qout[r*512+col]
// mode 1: kv scatter: col<512 -> bf16 kout[c][1+j][col], col>=512 -> fp32 vout
// ---------------------------------------------------------------------------
#define BM 64
#define BN 64
#define BKK 16

__global__ __launch_bounds__(256)
void gemm_ln_kernel(const float* __restrict__ X, const float* __restrict__ mu,
                    const float* __restrict__ rstd, const float* __restrict__ gamma,
                    const float* __restrict__ beta, const float* __restrict__ B,
                    int M, int N, int K, int mode,
                    __bf16* __restrict__ qout, __bf16* __restrict__ kout,
                    float* __restrict__ vout) {
    __shared__ float As[BKK][BM + 4];
    __shared__ float Bs[BKK][BN + 4];
    int tid = threadIdx.x;
    int tx = tid & 15, ty = tid >> 4;
    int bm = blockIdx.x, bn = blockIdx.y;
    float acc[4][4] = {};
    for (int kt = 0; kt < K; kt += BKK) {
        #pragma unroll
        for (int e = 0; e < (BM * BKK) / 256; ++e) {
            int idx = tid + e * 256;
            int kl = idx & 15, m = idx >> 4;
            int gr = bm * BM + m, gk = kt + kl;
            float v = X[(long long)gr * K + gk];
            As[kl][m] = (v - mu[gr]) * rstd[gr] * gamma[gk] + beta[gk];
        }
        #pragma unroll
        for (int e = 0; e < (BKK * BN) / 256; ++e) {
            int idx = tid + e * 256;
            int nl = idx & 63, kl = idx >> 6;
            Bs[kl][nl] = B[(long long)(kt + kl) * N + bn * BN + nl];
        }
        __syncthreads();
        #pragma unroll
        for (int kk = 0; kk < BKK; ++kk) {
            float4 a4 = *(const float4*)&As[kk][ty * 4];
            float4 b4 = *(const float4*)&Bs[kk][tx * 4];
            float a[4] = {a4.x, a4.y, a4.z, a4.w};
            float b[4] = {b4.x, b4.y, b4.z, b4.w};
            #pragma unroll
            for (int i = 0; i < 4; ++i)
                #pragma unroll
                for (int j = 0; j < 4; ++j)
                    acc[i][j] += a[i] * b[j];
        }
        __syncthreads();
    }
    #pragma unroll
    for (int i = 0; i < 4; ++i) {
        int gr = bm * BM + ty * 4 + i;
        #pragma unroll
        for (int j = 0; j < 4; ++j) {
            int gc = bn * BN + tx * 4 + j;
            float v = acc[i][j];
            if (mode == 0) {
                qout[(long long)gr * INNER + gc] = (__bf16)v;
            } else {
                int cc = gr / JLEN, jj = gr % JLEN;
                if (gc < INNER) kout[((long long)(cc * 128) + jj + 1) * INNER + gc] = (__bf16)v;
                else            vout[(long long)gr * INNER + (gc - INNER)] = v;
            }
        }
    }
}

// ---------------------------------------------------------------------------
// K5: wop = Wo @ Wp (512), bop = bo . Wp
// ---------------------------------------------------------------------------
__global__ void wop_kernel(const float* __restrict__ Wo, const float* __restrict__ bo,
                           const float* __restrict__ Wp, float* __restrict__ wop,
                           float* __restrict__ bop) {
    int r = blockIdx.x;  // 0..512; 512 -> bop
    const float* src = (r < INNER) ? (Wo + (long long)r * DH) : bo;
    float s = 0.f;
    for (int k = threadIdx.x; k < DH; k += blockDim.x) s += src[k] * Wp[k];
    for (int o = 32; o > 0; o >>= 1) s += __shfl_down(s, o);
    __shared__ float red[4];
    int lane = threadIdx.x & 63, w = threadIdx.x >> 6;
    if (lane == 0) red[w] = s;
    __syncthreads();
    if (threadIdx.x == 0) {
        float S = red[0] + red[1] + red[2] + red[3];
        if (r < INNER) wop[r] = S; else *bop = S;
    }
}

// ---------------------------------------------------------------------------
// K6: per-context prep: fill k_bf[c][0] = null_k, vp[c][h][j] = v . wop_h
// ---------------------------------------------------------------------------
__global__ void vp_prep_kernel(const float* __restrict__ v_all,
                               const float* __restrict__ null_v,
                               const float* __restrict__ null_k,
                               const float* __restrict__ wop,
                               float* __restrict__ vp, __bf16* __restrict__ k_bf) {
    int c = blockIdx.x;
    for (int d = threadIdx.x; d < INNER; d += blockDim.x)
        k_bf[(long long)(c * 128) * INNER + d] = (__bf16)null_k[d];
    for (int t = threadIdx.x; t < HEADS * 128; t += blockDim.x) {
        int h = t >> 7, j = t & 127;
        const float* vsrc = (j == 0)
            ? (null_v + h * DHEAD)
            : (v_all + ((long long)(c * JLEN + j - 1)) * INNER + h * DHEAD);
        const float* w = wop + h * DHEAD;
        float s = 0.f;
        #pragma unroll 8
        for (int d = 0; d < DHEAD; ++d) s += vsrc[d] * w[d];
        vp[(c * HEADS + h) * 128 + j] = s;
    }
}

// ---------------------------------------------------------------------------
// K7: attention via MFMA, no LDS. One block per (c,h); 4 independent waves.
// Each wave: all K B-frags in registers (64 VGPRs), streams 14 16-row q tiles.
// A layout: A[m=lane&15][k=quad*8+j]; B: n=lane&15, same k slots;
// D: col=lane&15, row=quad*4+reg  (verified layouts, learn_hip m89/m120).
// ---------------------------------------------------------------------------
__global__ __launch_bounds__(256)
void attn_mfma_kernel(const __bf16* __restrict__ qb, const __bf16* __restrict__ kb,
                      const float* __restrict__ vp, const int* __restrict__ mask,
                      float* __restrict__ s_buf) {
    int h = blockIdx.x & 7, c = blockIdx.x >> 3;
    int tid = threadIdx.x;
    int lane = tid & 63, w = tid >> 6;
    int n16 = lane & 15, quad = lane >> 4;

    const __bf16* kbase = kb + (long long)(c * 128) * INNER + h * DHEAD;
    bf16x8 bF[8][2];
    #pragma unroll
    for (int t = 0; t < 8; ++t)
        #pragma unroll
        for (int s = 0; s < 2; ++s)
            bF[t][s] = *(const bf16x8*)(kbase + (long long)(t * 16 + n16) * INNER + s * 32 + quad * 8);

    float vpv[8], am[8];
    #pragma unroll
    for (int t = 0; t < 8; ++t) {
        int col = t * 16 + n16;
        vpv[t] = vp[(c * HEADS + h) * 128 + col];
        am[t]  = (col == 0) ? 0.f : (mask[col - 1] ? 0.f : -3.0e38f);
    }

    const __bf16* qbase = qb + h * DHEAD;
    const f32x4 zero = {0.f, 0.f, 0.f, 0.f};
    for (int it = 0; it < 14; ++it) {
        int r0 = (it * 4 + w) * 16;
        const __bf16* qrow = qbase + (long long)(r0 + n16) * INNER + quad * 8;
        bf16x8 aF0 = *(const bf16x8*)(qrow);
        bf16x8 aF1 = *(const bf16x8*)(qrow + 32);
        f32x4 acc[8];
        #pragma unroll
        for (int t = 0; t < 8; ++t) {
            acc[t] = __builtin_amdgcn_mfma_f32_16x16x32_bf16(aF0, bF[t][0], zero,   0, 0, 0);
            acc[t] = __builtin_amdgcn_mfma_f32_16x16x32_bf16(aF1, bF[t][1], acc[t], 0, 0, 0);
        }
        #pragma unroll
        for (int r = 0; r < 4; ++r) {
            float sv[8];
            float m = -3.0e38f;
            #pragma unroll
            for (int t = 0; t < 8; ++t) {
                sv[t] = acc[t][r] * 0.125f + am[t];
                m = fmaxf(m, sv[t]);
            }
            #pragma unroll
            for (int o = 1; o < 16; o <<= 1) m = fmaxf(m, __shfl_xor(m, o, 16));
            float l = 0.f, p = 0.f;
            #pragma unroll
            for (int t = 0; t < 8; ++t) {
                float e = __expf(sv[t] - m);
                l += e; p += e * vpv[t];
            }
            #pragma unroll
            for (int o = 1; o < 16; o <<= 1) {
                l += __shfl_xor(l, o, 16);
                p += __shfl_xor(p, o, 16);
            }
            if (n16 == 0)
                s_buf[((long long)(c * HEADS + h)) * N_SEQ + r0 + quad * 4 + r] = p / l;
        }
    }
}

// ---------------------------------------------------------------------------
// K8: final: pred[n,c] = softplus(e_dot[n] + sum_h s[c,h,n] + bop + bp)
// ---------------------------------------------------------------------------
__global__ void final_kernel(const float* __restrict__ s_buf,
                             const float* __restrict__ e_dot,
                             const float* __restrict__ bop,
                             const float* __restrict__ bp,
                             float* __restrict__ out) {
    int t = blockIdx.x * blockDim.x + threadIdx.x;
    if (t >= N_SEQ * NCTX) return;
    int n = t >> 6, c = t & 63;
    float s = 0.f;
    #pragma unroll
    for (int h = 0; h < HEADS; ++h) s += s_buf[((long long)(c * HEADS + h)) * N_SEQ + n];
    float x = e_dot[n] + s + *bop + *bp;
    out[t] = fmaxf(x, 0.f) + log1pf(__expf(-fabsf(x)));
}

// ---------------------------------------------------------------------------
extern "C" void kernel_launch(void* const* d_in, const int* in_sizes, int n_in,
                              void* d_out, int out_size, void* d_ws, size_t ws_size,
                              hipStream_t stream) {
    const float* emb   = (const float*)d_in[0];
    const float* ctx   = (const float*)d_in[1];
    const int*   cmask = (const int*)  d_in[2];
    const float* qg    = (const float*)d_in[3];
    const float* qb_   = (const float*)d_in[4];
    const float* kvg   = (const float*)d_in[5];
    const float* kvb   = (const float*)d_in[6];
    const float* Wq    = (const float*)d_in[7];
    const float* Wkv   = (const float*)d_in[8];
    const float* nullk = (const float*)d_in[9];
    const float* nullv = (const float*)d_in[10];
    const float* Wo    = (const float*)d_in[11];
    const float* bo    = (const float*)d_in[12];
    const float* Wp    = (const float*)d_in[13];
    const float* bp    = (const float*)d_in[14];
    float* out  = (float*)d_out;
    float* ws_f = (float*)d_ws;

    float*  EMU   = ws_f + OFF_EMU;
    float*  ERSTD = ws_f + OFF_ERSTD;
    float*  EDOT  = ws_f + OFF_EDOT;
    float*  CMU   = ws_f + OFF_CMU;
    float*  CRSTD = ws_f + OFF_CRSTD;
    __bf16* QBF   = (__bf16*)(ws_f + OFF_QBF);
    __bf16* KBF   = (__bf16*)(ws_f + OFF_KBF);
    float*  VALL  = ws_f + OFF_VALL;
    float*  VP    = ws_f + OFF_VP;
    float*  WOP   = ws_f + OFF_WOP;
    float*  BOP   = ws_f + OFF_BOP;
    float*  SBUF  = ws_f + OFF_SBUF;

    row_stats_kernel<<<N_SEQ, 256, 0, stream>>>(emb, DH, Wp, EMU, ERSTD, EDOT);
    row_stats_kernel<<<NCTX * JLEN, 256, 0, stream>>>(ctx, DC, nullptr, CMU, CRSTD, nullptr);
    gemm_ln_kernel<<<dim3(N_SEQ / BM, INNER / BN), 256, 0, stream>>>(
        emb, EMU, ERSTD, qg, qb_, Wq, N_SEQ, INNER, DH, 0, QBF, nullptr, nullptr);
    gemm_ln_kernel<<<dim3((NCTX * JLEN) / BM, (2 * INNER) / BN), 256, 0, stream>>>(
        ctx, CMU, CRSTD, kvg, kvb, Wkv, NCTX * JLEN, 2 * INNER, DC, 1, nullptr, KBF, VALL);
    wop_kernel<<<INNER + 1, 256, 0, stream>>>(Wo, bo, Wp, WOP, BOP);
    vp_prep_kernel<<<NCTX, 256, 0, stream>>>(VALL, nullv, nullk, WOP, VP, KBF);
    attn_mfma_kernel<<<NCTX * HEADS, 256, 0, stream>>>(QBF, KBF, VP, cmask, SBUF);
    final_kernel<<<(N_SEQ * NCTX + 255) / 256, 256, 0, stream>>>(SBUF, EDOT, BOP, bp, out);
}

// Round 3
// 312.077 us; speedup vs baseline: 10.3701x; 2.3805x over previous
//
#include <hip/hip_runtime.h>
#include <math.h>

// ---------------------------------------------------------------------------
// Problem constants
// ---------------------------------------------------------------------------
#define N_SEQ   896
#define DH      3072
#define NCTX    64
#define JLEN    127
#define DC      1024
#define HEADS   8
#define DHEAD   64
#define INNER   512   // HEADS*DHEAD
#define MKV     8128  // NCTX*JLEN
#define MKVPAD  8192

typedef __bf16 bf16x8 __attribute__((ext_vector_type(8)));
typedef float  f32x4  __attribute__((ext_vector_type(4)));

// workspace float offsets
#define OFF_EDOT   0LL
#define OFF_QBF    (OFF_EDOT  + N_SEQ)
#define OFF_KBF    (OFF_QBF   + (long long)N_SEQ*INNER/2)       // bf16 896x512
#define OFF_VALL   (OFF_KBF   + (long long)NCTX*128*INNER/2)    // bf16 64x128x512
#define OFF_VP     (OFF_VALL  + (long long)MKV*INNER)           // fp32 8128x512
#define OFF_WOP    (OFF_VP    + NCTX*HEADS*128)
#define OFF_BOP    (OFF_WOP   + INNER)
#define OFF_SBUF   (OFF_BOP   + 16)                             // fp32 64*8*896
#define OFF_ANQ    (OFF_SBUF  + (long long)NCTX*HEADS*N_SEQ)    // bf16 896x3072
#define OFF_ANKV   (OFF_ANQ   + (long long)N_SEQ*DH/2)          // bf16 8192x1024
#define OFF_WQT    (OFF_ANKV  + (long long)MKVPAD*DC/2)         // bf16 512x3072
#define OFF_WKVT   (OFF_WQT   + (long long)INNER*DH/2)          // bf16 1024x1024

// ---------------------------------------------------------------------------
// async global->LDS 16B helper
// ---------------------------------------------------------------------------
__device__ __forceinline__ void async_copy16(const __bf16* g, __bf16* l) {
    __builtin_amdgcn_global_load_lds(
        (const __attribute__((address_space(1))) unsigned int*)g,
        (__attribute__((address_space(3))) unsigned int*)l,
        16, 0, 0);
}

// ---------------------------------------------------------------------------
// K1: fused layernorm stats + normalize + bf16 convert (+ optional Wp dot)
// one block per row
// ---------------------------------------------------------------------------
__global__ __launch_bounds__(256)
void ln_bf16_kernel(const float* __restrict__ X, int K,
                    const float* __restrict__ gamma, const float* __restrict__ beta,
                    const float* __restrict__ wp,
                    __bf16* __restrict__ out, float* __restrict__ dotout) {
    int row = blockIdx.x;
    const float* x = X + (long long)row * K;
    float s = 0.f, ss = 0.f, dp = 0.f;
    for (int k = threadIdx.x; k < K; k += 256) {
        float v = x[k];
        s += v; ss += v * v;
        if (wp) dp += v * wp[k];
    }
    #pragma unroll
    for (int o = 32; o > 0; o >>= 1) {
        s  += __shfl_down(s,  o);
        ss += __shfl_down(ss, o);
        dp += __shfl_down(dp, o);
    }
    __shared__ float red[3][4];
    __shared__ float sh_mu, sh_rstd;
    int lane = threadIdx.x & 63, w = threadIdx.x >> 6;
    if (lane == 0) { red[0][w] = s; red[1][w] = ss; red[2][w] = dp; }
    __syncthreads();
    if (threadIdx.x == 0) {
        float S = red[0][0] + red[0][1] + red[0][2] + red[0][3];
        float SS = red[1][0] + red[1][1] + red[1][2] + red[1][3];
        float m = S / K;
        sh_mu = m;
        sh_rstd = rsqrtf(SS / K - m * m + 1e-5f);
        if (dotout) dotout[row] = red[2][0] + red[2][1] + red[2][2] + red[2][3];
    }
    __syncthreads();
    float m = sh_mu, r = sh_rstd;
    __bf16* o = out + (long long)row * K;
    for (int k = threadIdx.x; k < K; k += 256)
        o[k] = (__bf16)((x[k] - m) * r * gamma[k] + beta[k]);
}

// ---------------------------------------------------------------------------
// K2: transpose fp32 (R x C) -> bf16 (C x R)
// ---------------------------------------------------------------------------
__global__ __launch_bounds__(256)
void transpose_bf16_kernel(const float* __restrict__ B, int R, int C,
                           __bf16* __restrict__ Bt) {
    __shared__ float t[32][33];
    int rb = blockIdx.x * 32, cb = blockIdx.y * 32;
    int tx = threadIdx.x & 31, ty = threadIdx.x >> 5;  // 8 rows per pass
    #pragma unroll
    for (int i = 0; i < 32; i += 8)
        t[ty + i][tx] = B[(long long)(rb + ty + i) * C + cb + tx];
    __syncthreads();
    #pragma unroll
    for (int i = 0; i < 32; i += 8)
        Bt[(long long)(cb + ty + i) * R + rb + tx] = (__bf16)t[tx][ty + i];
}

// ---------------------------------------------------------------------------
// K3: bf16 MFMA GEMM, m97 structure: 128x128 tile, BK=32, global_load_lds,
// 4 waves x (4x4 of 16x16x32). A: MxK bf16, Bt: NxK bf16 (pre-transposed).
// mode 0: qout[gr*512+gc] bf16
// mode 1: kv scatter (gr<Mvalid): gc<512 -> bf16 kout[c][1+j][gc], else fp32 vout
// ---------------------------------------------------------------------------
__global__ __launch_bounds__(256)
void mfma_gemm_kernel(const __bf16* __restrict__ A, const __bf16* __restrict__ Bt,
                      int K, int mode, int Mvalid,
                      __bf16* __restrict__ qout, __bf16* __restrict__ kout,
                      float* __restrict__ vout) {
    __shared__ __align__(16) __bf16 As[128 * 32];
    __shared__ __align__(16) __bf16 Bs[128 * 32];
    int tid = threadIdx.x;
    int lane = tid & 63, w = tid >> 6;
    int n16 = lane & 15, quad = lane >> 4;
    int wr = (w >> 1) * 64, wc = (w & 1) * 64;
    long long m0 = (long long)blockIdx.x * 128;
    long long n0 = (long long)blockIdx.y * 128;

    const __bf16* aG = A  + (m0 + (tid >> 2)) * K + (tid & 3) * 8;
    const __bf16* bG = Bt + (n0 + (tid >> 2)) * K + (tid & 3) * 8;
    __bf16* aL = As + tid * 8;
    __bf16* bL = Bs + tid * 8;

    f32x4 acc[4][4];
    const f32x4 z = {0.f, 0.f, 0.f, 0.f};
    #pragma unroll
    for (int i = 0; i < 4; ++i)
        #pragma unroll
        for (int j = 0; j < 4; ++j) acc[i][j] = z;

    for (int k0 = 0; k0 < K; k0 += 32) {
        async_copy16(aG + k0, aL);
        async_copy16(aG + (long long)64 * K + k0, aL + 2048);
        async_copy16(bG + k0, bL);
        async_copy16(bG + (long long)64 * K + k0, bL + 2048);
        __syncthreads();
        bf16x8 af[4], bfr[4];
        #pragma unroll
        for (int i = 0; i < 4; ++i)
            af[i]  = *(const bf16x8*)&As[(wr + i * 16 + n16) * 32 + quad * 8];
        #pragma unroll
        for (int j = 0; j < 4; ++j)
            bfr[j] = *(const bf16x8*)&Bs[(wc + j * 16 + n16) * 32 + quad * 8];
        #pragma unroll
        for (int i = 0; i < 4; ++i)
            #pragma unroll
            for (int j = 0; j < 4; ++j)
                acc[i][j] = __builtin_amdgcn_mfma_f32_16x16x32_bf16(af[i], bfr[j], acc[i][j], 0, 0, 0);
        __syncthreads();
    }

    #pragma unroll
    for (int i = 0; i < 4; ++i) {
        #pragma unroll
        for (int r = 0; r < 4; ++r) {
            long long gr = m0 + wr + i * 16 + quad * 4 + r;
            if (mode == 1 && gr >= Mvalid) continue;
            int cc = 0, jj = 0;
            if (mode == 1) { cc = (int)(gr / JLEN); jj = (int)(gr % JLEN); }
            #pragma unroll
            for (int j = 0; j < 4; ++j) {
                long long gc = n0 + wc + j * 16 + n16;
                float v = acc[i][j][r];
                if (mode == 0) {
                    qout[gr * INNER + gc] = (__bf16)v;
                } else if (gc < INNER) {
                    kout[((long long)(cc * 128) + jj + 1) * INNER + gc] = (__bf16)v;
                } else {
                    vout[gr * INNER + (gc - INNER)] = v;
                }
            }
        }
    }
}

// ---------------------------------------------------------------------------
// K4: wop = Wo @ Wp (512), bop = bo . Wp
// ---------------------------------------------------------------------------
__global__ void wop_kernel(const float* __restrict__ Wo, const float* __restrict__ bo,
                           const float* __restrict__ Wp, float* __restrict__ wop,
                           float* __restrict__ bop) {
    int r = blockIdx.x;  // 0..512; 512 -> bop
    const float* src = (r < INNER) ? (Wo + (long long)r * DH) : bo;
    float s = 0.f;
    for (int k = threadIdx.x; k < DH; k += blockDim.x) s += src[k] * Wp[k];
    for (int o = 32; o > 0; o >>= 1) s += __shfl_down(s, o);
    __shared__ float red[4];
    int lane = threadIdx.x & 63, w = threadIdx.x >> 6;
    if (lane == 0) red[w] = s;
    __syncthreads();
    if (threadIdx.x == 0) {
        float S = red[0] + red[1] + red[2] + red[3];
        if (r < INNER) wop[r] = S; else *bop = S;
    }
}

// ---------------------------------------------------------------------------
// K5: per-context prep: fill k_bf[c][0] = null_k, vp[c][h][j] = v . wop_h
// ---------------------------------------------------------------------------
__global__ void vp_prep_kernel(const float* __restrict__ v_all,
                               const float* __restrict__ null_v,
                               const float* __restrict__ null_k,
                               const float* __restrict__ wop,
                               float* __restrict__ vp, __bf16* __restrict__ k_bf) {
    int c = blockIdx.x;
    for (int d = threadIdx.x; d < INNER; d += blockDim.x)
        k_bf[(long long)(c * 128) * INNER + d] = (__bf16)null_k[d];
    for (int t = threadIdx.x; t < HEADS * 128; t += blockDim.x) {
        int h = t >> 7, j = t & 127;
        const float* vsrc = (j == 0)
            ? (null_v + h * DHEAD)
            : (v_all + ((long long)(c * JLEN + j - 1)) * INNER + h * DHEAD);
        const float* w = wop + h * DHEAD;
        float s = 0.f;
        #pragma unroll 8
        for (int d = 0; d < DHEAD; ++d) s += vsrc[d] * w[d];
        vp[(c * HEADS + h) * 128 + j] = s;
    }
}

// ---------------------------------------------------------------------------
// K6: attention via MFMA, no LDS. One block per (c,h); 4 independent waves.
// ---------------------------------------------------------------------------
__global__ __launch_bounds__(256)
void attn_mfma_kernel(const __bf16* __restrict__ qb, const __bf16* __restrict__ kb,
                      const float* __restrict__ vp, const int* __restrict__ mask,
                      float* __restrict__ s_buf) {
    int h = blockIdx.x & 7, c = blockIdx.x >> 3;
    int tid = threadIdx.x;
    int lane = tid & 63, w = tid >> 6;
    int n16 = lane & 15, quad = lane >> 4;

    const __bf16* kbase = kb + (long long)(c * 128) * INNER + h * DHEAD;
    bf16x8 bF[8][2];
    #pragma unroll
    for (int t = 0; t < 8; ++t)
        #pragma unroll
        for (int s = 0; s < 2; ++s)
            bF[t][s] = *(const bf16x8*)(kbase + (long long)(t * 16 + n16) * INNER + s * 32 + quad * 8);

    float vpv[8], am[8];
    #pragma unroll
    for (int t = 0; t < 8; ++t) {
        int col = t * 16 + n16;
        vpv[t] = vp[(c * HEADS + h) * 128 + col];
        am[t]  = (col == 0) ? 0.f : (mask[col - 1] ? 0.f : -3.0e38f);
    }

    const __bf16* qbase = qb + h * DHEAD;
    const f32x4 zero = {0.f, 0.f, 0.f, 0.f};
    for (int it = 0; it < 14; ++it) {
        int r0 = (it * 4 + w) * 16;
        const __bf16* qrow = qbase + (long long)(r0 + n16) * INNER + quad * 8;
        bf16x8 aF0 = *(const bf16x8*)(qrow);
        bf16x8 aF1 = *(const bf16x8*)(qrow + 32);
        f32x4 acc[8];
        #pragma unroll
        for (int t = 0; t < 8; ++t) {
            acc[t] = __builtin_amdgcn_mfma_f32_16x16x32_bf16(aF0, bF[t][0], zero,   0, 0, 0);
            acc[t] = __builtin_amdgcn_mfma_f32_16x16x32_bf16(aF1, bF[t][1], acc[t], 0, 0, 0);
        }
        #pragma unroll
        for (int r = 0; r < 4; ++r) {
            float sv[8];
            float m = -3.0e38f;
            #pragma unroll
            for (int t = 0; t < 8; ++t) {
                sv[t] = acc[t][r] * 0.125f + am[t];
                m = fmaxf(m, sv[t]);
            }
            #pragma unroll
            for (int o = 1; o < 16; o <<= 1) m = fmaxf(m, __shfl_xor(m, o, 16));
            float l = 0.f, p = 0.f;
            #pragma unroll
            for (int t = 0; t < 8; ++t) {
                float e = __expf(sv[t] - m);
                l += e; p += e * vpv[t];
            }
            #pragma unroll
            for (int o = 1; o < 16; o <<= 1) {
                l += __shfl_xor(l, o, 16);
                p += __shfl_xor(p, o, 16);
            }
            if (n16 == 0)
                s_buf[((long long)(c * HEADS + h)) * N_SEQ + r0 + quad * 4 + r] = p / l;
        }
    }
}

// ---------------------------------------------------------------------------
// K7: final: pred[n,c] = softplus(e_dot[n] + sum_h s[c,h,n] + bop + bp)
// ---------------------------------------------------------------------------
__global__ void final_kernel(const float* __restrict__ s_buf,
                             const float* __restrict__ e_dot,
                             const float* __restrict__ bop,
                             const float* __restrict__ bp,
                             float* __restrict__ out) {
    int t = blockIdx.x * blockDim.x + threadIdx.x;
    if (t >= N_SEQ * NCTX) return;
    int n = t >> 6, c = t & 63;
    float s = 0.f;
    #pragma unroll
    for (int h = 0; h < HEADS; ++h) s += s_buf[((long long)(c * HEADS + h)) * N_SEQ + n];
    float x = e_dot[n] + s + *bop + *bp;
    out[t] = fmaxf(x, 0.f) + log1pf(__expf(-fabsf(x)));
}

// ---------------------------------------------------------------------------
extern "C" void kernel_launch(void* const* d_in, const int* in_sizes, int n_in,
                              void* d_out, int out_size, void* d_ws, size_t ws_size,
                              hipStream_t stream) {
    const float* emb   = (const float*)d_in[0];
    const float* ctx   = (const float*)d_in[1];
    const int*   cmask = (const int*)  d_in[2];
    const float* qg    = (const float*)d_in[3];
    const float* qb_   = (const float*)d_in[4];
    const float* kvg   = (const float*)d_in[5];
    const float* kvb   = (const float*)d_in[6];
    const float* Wq    = (const float*)d_in[7];
    const float* Wkv   = (const float*)d_in[8];
    const float* nullk = (const float*)d_in[9];
    const float* nullv = (const float*)d_in[10];
    const float* Wo    = (const float*)d_in[11];
    const float* bo    = (const float*)d_in[12];
    const float* Wp    = (const float*)d_in[13];
    const float* bp    = (const float*)d_in[14];
    float* out  = (float*)d_out;
    float* ws_f = (float*)d_ws;

    float*  EDOT  = ws_f + OFF_EDOT;
    __bf16* QBF   = (__bf16*)(ws_f + OFF_QBF);
    __bf16* KBF   = (__bf16*)(ws_f + OFF_KBF);
    float*  VALL  = ws_f + OFF_VALL;
    float*  VP    = ws_f + OFF_VP;
    float*  WOP   = ws_f + OFF_WOP;
    float*  BOP   = ws_f + OFF_BOP;
    float*  SBUF  = ws_f + OFF_SBUF;
    __bf16* ANQ   = (__bf16*)(ws_f + OFF_ANQ);
    __bf16* ANKV  = (__bf16*)(ws_f + OFF_ANKV);
    __bf16* WQT   = (__bf16*)(ws_f + OFF_WQT);
    __bf16* WKVT  = (__bf16*)(ws_f + OFF_WKVT);

    ln_bf16_kernel<<<N_SEQ, 256, 0, stream>>>(emb, DH, qg, qb_, Wp, ANQ, EDOT);
    ln_bf16_kernel<<<MKV, 256, 0, stream>>>(ctx, DC, kvg, kvb, nullptr, ANKV, nullptr);
    transpose_bf16_kernel<<<dim3(DH / 32, INNER / 32), 256, 0, stream>>>(Wq, DH, INNER, WQT);
    transpose_bf16_kernel<<<dim3(DC / 32, (2 * INNER) / 32), 256, 0, stream>>>(Wkv, DC, 2 * INNER, WKVT);
    mfma_gemm_kernel<<<dim3(N_SEQ / 128, INNER / 128), 256, 0, stream>>>(
        ANQ, WQT, DH, 0, N_SEQ, QBF, nullptr, nullptr);
    mfma_gemm_kernel<<<dim3(MKVPAD / 128, (2 * INNER) / 128), 256, 0, stream>>>(
        ANKV, WKVT, DC, 1, MKV, nullptr, KBF, VALL);
    wop_kernel<<<INNER + 1, 256, 0, stream>>>(Wo, bo, Wp, WOP, BOP);
    vp_prep_kernel<<<NCTX, 256, 0, stream>>>(VALL, nullv, nullk, WOP, VP, KBF);
    attn_mfma_kernel<<<NCTX * HEADS, 256, 0, stream>>>(QBF, KBF, VP, cmask, SBUF);
    final_kernel<<<(N_SEQ * NCTX + 255) / 256, 256, 0, stream>>>(SBUF, EDOT, BOP, bp, out);
}

// Round 4
// 237.310 us; speedup vs baseline: 13.6373x; 1.3151x over previous
//
#include <hip/hip_runtime.h>
#include <math.h>

// ---------------------------------------------------------------------------
// Problem constants
// ---------------------------------------------------------------------------
#define N_SEQ   896
#define DH      3072
#define NCTX    64
#define JLEN    127
#define DC      1024
#define HEADS   8
#define DHEAD   64
#define INNER   512   // HEADS*DHEAD
#define MKV     8128  // NCTX*JLEN
#define MKVPAD  8192

typedef __bf16 bf16x8 __attribute__((ext_vector_type(8)));
typedef float  f32x4  __attribute__((ext_vector_type(4)));

// workspace float offsets
#define OFF_EDOT   0LL
#define OFF_QBF    (OFF_EDOT + N_SEQ)
#define OFF_KBF    (OFF_QBF  + (long long)N_SEQ*INNER/2)     // bf16 896x512
#define OFF_VPM    (OFF_KBF  + (long long)NCTX*128*INNER/2)  // fp32 8128x8
#define OFF_VPNULL (OFF_VPM  + (long long)MKV*8)
#define OFF_WOP    (OFF_VPNULL + 8)
#define OFF_BOP    (OFF_WOP  + INNER)
#define OFF_SBUF   (OFF_BOP  + 16)                           // fp32 64*8*896
#define OFF_ANQ    (OFF_SBUF + (long long)NCTX*HEADS*N_SEQ)  // bf16 896x3072
#define OFF_ANKV   (OFF_ANQ  + (long long)N_SEQ*DH/2)        // bf16 8192x1024
#define OFF_WQT    (OFF_ANKV + (long long)MKVPAD*DC/2)       // bf16 512x3072
#define OFF_WKT    (OFF_WQT  + (long long)INNER*DH/2)        // bf16 512x1024
#define OFF_WVPT   (OFF_WKT  + (long long)INNER*DC/2)        // bf16 16x1024
#define OFF_QSL    (OFF_WVPT + 16*1024/2)                    // fp32 8 x 896x512

// ---------------------------------------------------------------------------
// async global->LDS 16B helper
// ---------------------------------------------------------------------------
__device__ __forceinline__ void async_copy16(const __bf16* g, __bf16* l) {
    __builtin_amdgcn_global_load_lds(
        (const __attribute__((address_space(1))) unsigned int*)g,
        (__attribute__((address_space(3))) unsigned int*)l,
        16, 0, 0);
}

// ---------------------------------------------------------------------------
// K1: fused layernorm stats + normalize + bf16 convert (+ optional Wp dot)
// one block per row; P = K/1024 float4 passes; x cached in registers
// ---------------------------------------------------------------------------
template <int P>
__global__ __launch_bounds__(256)
void ln_bf16_kernel(const float* __restrict__ X,
                    const float* __restrict__ gamma, const float* __restrict__ beta,
                    const float* __restrict__ wp,
                    __bf16* __restrict__ out, float* __restrict__ dotout) {
    const int K = P * 1024;
    int row = blockIdx.x;
    const float* x = X + (long long)row * K;
    float4 xv[P];
    float s = 0.f, ss = 0.f, dp = 0.f;
    #pragma unroll
    for (int p = 0; p < P; ++p) {
        xv[p] = *(const float4*)&x[p * 1024 + threadIdx.x * 4];
        s  += xv[p].x + xv[p].y + xv[p].z + xv[p].w;
        ss += xv[p].x * xv[p].x + xv[p].y * xv[p].y
            + xv[p].z * xv[p].z + xv[p].w * xv[p].w;
        if (wp) {
            float4 w4 = *(const float4*)&wp[p * 1024 + threadIdx.x * 4];
            dp += xv[p].x * w4.x + xv[p].y * w4.y + xv[p].z * w4.z + xv[p].w * w4.w;
        }
    }
    #pragma unroll
    for (int o = 32; o > 0; o >>= 1) {
        s  += __shfl_down(s,  o);
        ss += __shfl_down(ss, o);
        dp += __shfl_down(dp, o);
    }
    __shared__ float red[3][4];
    __shared__ float sh_mu, sh_rstd;
    int lane = threadIdx.x & 63, w = threadIdx.x >> 6;
    if (lane == 0) { red[0][w] = s; red[1][w] = ss; red[2][w] = dp; }
    __syncthreads();
    if (threadIdx.x == 0) {
        float S  = red[0][0] + red[0][1] + red[0][2] + red[0][3];
        float SS = red[1][0] + red[1][1] + red[1][2] + red[1][3];
        float m = S / K;
        sh_mu = m;
        sh_rstd = rsqrtf(SS / K - m * m + 1e-5f);
        if (dotout) dotout[row] = red[2][0] + red[2][1] + red[2][2] + red[2][3];
    }
    __syncthreads();
    float m = sh_mu, r = sh_rstd;
    __bf16* o = out + (long long)row * K;
    #pragma unroll
    for (int p = 0; p < P; ++p) {
        int col = p * 1024 + threadIdx.x * 4;
        float4 g4 = *(const float4*)&gamma[col];
        float4 b4 = *(const float4*)&beta[col];
        __bf16 ov[4];
        ov[0] = (__bf16)((xv[p].x - m) * r * g4.x + b4.x);
        ov[1] = (__bf16)((xv[p].y - m) * r * g4.y + b4.y);
        ov[2] = (__bf16)((xv[p].z - m) * r * g4.z + b4.z);
        ov[3] = (__bf16)((xv[p].w - m) * r * g4.w + b4.w);
        *(ushort4*)&o[col] = *(ushort4*)ov;
    }
}

// ---------------------------------------------------------------------------
// K2: transpose fp32 (R x C) -> bf16 (C x R), row stride C, out stride R
// ---------------------------------------------------------------------------
__global__ __launch_bounds__(256)
void transpose_bf16_kernel(const float* __restrict__ B, int R, int C,
                           __bf16* __restrict__ Bt) {
    __shared__ float t[32][33];
    int rb = blockIdx.x * 32, cb = blockIdx.y * 32;
    int tx = threadIdx.x & 31, ty = threadIdx.x >> 5;  // 8 rows per pass
    #pragma unroll
    for (int i = 0; i < 32; i += 8)
        t[ty + i][tx] = B[(long long)(rb + ty + i) * C + cb + tx];
    __syncthreads();
    #pragma unroll
    for (int i = 0; i < 32; i += 8)
        Bt[(long long)(cb + ty + i) * R + rb + tx] = (__bf16)t[tx][ty + i];
}

// ---------------------------------------------------------------------------
// K3: wop = Wo @ Wp (512), bop = bo . Wp
// ---------------------------------------------------------------------------
__global__ void wop_kernel(const float* __restrict__ Wo, const float* __restrict__ bo,
                           const float* __restrict__ Wp, float* __restrict__ wop,
                           float* __restrict__ bop) {
    int r = blockIdx.x;  // 0..512; 512 -> bop
    const float* src = (r < INNER) ? (Wo + (long long)r * DH) : bo;
    float s = 0.f;
    for (int k = threadIdx.x; k < DH; k += blockDim.x) s += src[k] * Wp[k];
    for (int o = 32; o > 0; o >>= 1) s += __shfl_down(s, o);
    __shared__ float red[4];
    int lane = threadIdx.x & 63, w = threadIdx.x >> 6;
    if (lane == 0) red[w] = s;
    __syncthreads();
    if (threadIdx.x == 0) {
        float S = red[0] + red[1] + red[2] + red[3];
        if (r < INNER) wop[r] = S; else *bop = S;
    }
}

// ---------------------------------------------------------------------------
// K4: wvpt[h][k] = sum_d Wkv[k][512+h*64+d]*wop[h*64+d] (bf16, B^T layout,
// rows 8..15 zero); also null-k rows of KBF and vpnull[h]
// ---------------------------------------------------------------------------
__global__ void wvp_kernel(const float* __restrict__ Wkv, const float* __restrict__ wop,
                           const float* __restrict__ null_v, const float* __restrict__ null_k,
                           __bf16* __restrict__ wvpt, float* __restrict__ vpnull,
                           __bf16* __restrict__ k_bf) {
    int bx = blockIdx.x;
    if (bx < 32) {
        int t = bx * 256 + threadIdx.x;          // 0..8191
        int k = t >> 3, h = t & 7;
        const float* src = Wkv + (long long)k * (2 * INNER) + INNER + h * 64;
        const float* wv  = wop + h * 64;
        float s = 0.f;
        #pragma unroll 16
        for (int d = 0; d < 64; ++d) s += src[d] * wv[d];
        wvpt[h * 1024 + k] = (__bf16)s;
    } else {
        for (int i = threadIdx.x; i < 8 * 1024; i += 256)
            wvpt[8 * 1024 + i] = (__bf16)0.f;
        for (int i = threadIdx.x; i < NCTX * INNER; i += 256) {
            int c = i >> 9, d = i & 511;
            k_bf[(long long)(c * 128) * INNER + d] = (__bf16)null_k[d];
        }
        if (threadIdx.x < 8) {
            int h = threadIdx.x;
            float s = 0.f;
            #pragma unroll 16
            for (int d = 0; d < 64; ++d) s += null_v[h * 64 + d] * wop[h * 64 + d];
            vpnull[h] = s;
        }
    }
}

// ---------------------------------------------------------------------------
// K5: merged projection GEMM (bf16 MFMA, 128x128 tile, BK=32, global_load_lds)
// blocks [0,224):   q split-K=8 -> fp32 slice qsl[s][896][512]
// blocks [224,480): k GEMM 8192x512x1024 -> bf16 KBF scatter; n0==0 blocks
//                   also compute vp via an extra WVPT B-fragment (cols 0..7)
// ---------------------------------------------------------------------------
__global__ __launch_bounds__(256)
void proj_kernel(const __bf16* __restrict__ ANQ, const __bf16* __restrict__ WQT,
                 const __bf16* __restrict__ ANKV, const __bf16* __restrict__ WKT,
                 const __bf16* __restrict__ WVPT,
                 float* __restrict__ qsl, __bf16* __restrict__ kout,
                 float* __restrict__ vpm) {
    __shared__ __align__(16) __bf16 As[128 * 32];
    __shared__ __align__(16) __bf16 Bs[128 * 32];
    int b = blockIdx.x;
    int tid = threadIdx.x;
    int lane = tid & 63, w = tid >> 6;
    int n16 = lane & 15, quad = lane >> 4;
    int wr = (w >> 1) * 64, wc = (w & 1) * 64;

    const __bf16 *A, *B;
    int K, kbeg, kend, mode, slice = 0;
    long long m0, n0;
    if (b < 224) {
        mode = 0; slice = b / 28;
        int rem = b % 28;
        m0 = (long long)(rem % 7) * 128;
        n0 = (long long)(rem / 7) * 128;
        K = DH; kbeg = slice * 384; kend = kbeg + 384;
        A = ANQ; B = WQT;
    } else {
        mode = 1;
        int b2 = b - 224;
        m0 = (long long)(b2 & 63) * 128;
        n0 = (long long)(b2 >> 6) * 128;
        K = DC; kbeg = 0; kend = DC;
        A = ANKV; B = WKT;
    }
    bool dovp = (mode == 1) && (n0 == 0);

    const __bf16* aG = A + (m0 + (tid >> 2)) * K + (tid & 3) * 8;
    const __bf16* bG = B + (n0 + (tid >> 2)) * K + (tid & 3) * 8;
    __bf16* aL = As + tid * 8;
    __bf16* bL = Bs + tid * 8;

    f32x4 acc[4][4], accv[4];
    const f32x4 z = {0.f, 0.f, 0.f, 0.f};
    #pragma unroll
    for (int i = 0; i < 4; ++i) {
        accv[i] = z;
        #pragma unroll
        for (int j = 0; j < 4; ++j) acc[i][j] = z;
    }

    for (int k0 = kbeg; k0 < kend; k0 += 32) {
        async_copy16(aG + k0, aL);
        async_copy16(aG + (long long)64 * K + k0, aL + 2048);
        async_copy16(bG + k0, bL);
        async_copy16(bG + (long long)64 * K + k0, bL + 2048);
        bf16x8 bv;
        if (dovp) bv = *(const bf16x8*)&WVPT[n16 * 1024 + k0 + quad * 8];
        __syncthreads();
        bf16x8 af[4], bfr[4];
        #pragma unroll
        for (int i = 0; i < 4; ++i)
            af[i]  = *(const bf16x8*)&As[(wr + i * 16 + n16) * 32 + quad * 8];
        #pragma unroll
        for (int j = 0; j < 4; ++j)
            bfr[j] = *(const bf16x8*)&Bs[(wc + j * 16 + n16) * 32 + quad * 8];
        #pragma unroll
        for (int i = 0; i < 4; ++i)
            #pragma unroll
            for (int j = 0; j < 4; ++j)
                acc[i][j] = __builtin_amdgcn_mfma_f32_16x16x32_bf16(af[i], bfr[j], acc[i][j], 0, 0, 0);
        if (dovp) {
            #pragma unroll
            for (int i = 0; i < 4; ++i)
                accv[i] = __builtin_amdgcn_mfma_f32_16x16x32_bf16(af[i], bv, accv[i], 0, 0, 0);
        }
        __syncthreads();
    }

    if (mode == 0) {
        float* qdst = qsl + (long long)slice * (N_SEQ * INNER);
        #pragma unroll
        for (int i = 0; i < 4; ++i)
            #pragma unroll
            for (int r = 0; r < 4; ++r) {
                long long gr = m0 + wr + i * 16 + quad * 4 + r;
                #pragma unroll
                for (int j = 0; j < 4; ++j) {
                    long long gc = n0 + wc + j * 16 + n16;
                    qdst[gr * INNER + gc] = acc[i][j][r];
                }
            }
    } else {
        #pragma unroll
        for (int i = 0; i < 4; ++i)
            #pragma unroll
            for (int r = 0; r < 4; ++r) {
                long long gr = m0 + wr + i * 16 + quad * 4 + r;
                if (gr >= MKV) continue;
                int cc = (int)(gr / JLEN), jj = (int)(gr % JLEN);
                #pragma unroll
                for (int j = 0; j < 4; ++j) {
                    long long gc = n0 + wc + j * 16 + n16;
                    kout[((long long)(cc * 128) + jj + 1) * INNER + gc] = (__bf16)acc[i][j][r];
                }
                if (dovp && n16 < 8) vpm[gr * 8 + n16] = accv[i][r];
            }
    }
}

// ---------------------------------------------------------------------------
// K6: reduce 8 q split-K slices -> bf16
// ---------------------------------------------------------------------------
__global__ void qreduce_kernel(const float* __restrict__ qsl, __bf16* __restrict__ qbf) {
    int t = blockIdx.x * 256 + threadIdx.x;   // 458752 total
    float s = 0.f;
    #pragma unroll
    for (int k = 0; k < 8; ++k) s += qsl[(long long)k * (N_SEQ * INNER) + t];
    qbf[t] = (__bf16)s;
}

// ---------------------------------------------------------------------------
// K7: attention via MFMA, no LDS. One block per (c,h); 4 independent waves.
// ---------------------------------------------------------------------------
__global__ __launch_bounds__(256)
void attn_mfma_kernel(const __bf16* __restrict__ qb, const __bf16* __restrict__ kb,
                      const float* __restrict__ vpm, const float* __restrict__ vpnull,
                      const int* __restrict__ mask, float* __restrict__ s_buf) {
    int h = blockIdx.x & 7, c = blockIdx.x >> 3;
    int tid = threadIdx.x;
    int lane = tid & 63, w = tid >> 6;
    int n16 = lane & 15, quad = lane >> 4;

    const __bf16* kbase = kb + (long long)(c * 128) * INNER + h * DHEAD;
    bf16x8 bF[8][2];
    #pragma unroll
    for (int t = 0; t < 8; ++t)
        #pragma unroll
        for (int s = 0; s < 2; ++s)
            bF[t][s] = *(const bf16x8*)(kbase + (long long)(t * 16 + n16) * INNER + s * 32 + quad * 8);

    float vpv[8], am[8];
    #pragma unroll
    for (int t = 0; t < 8; ++t) {
        int col = t * 16 + n16;
        vpv[t] = (col == 0) ? vpnull[h] : vpm[(long long)(c * JLEN + col - 1) * 8 + h];
        am[t]  = (col == 0) ? 0.f : (mask[col - 1] ? 0.f : -3.0e38f);
    }

    const __bf16* qbase = qb + h * DHEAD;
    const f32x4 zero = {0.f, 0.f, 0.f, 0.f};
    for (int it = 0; it < 14; ++it) {
        int r0 = (it * 4 + w) * 16;
        const __bf16* qrow = qbase + (long long)(r0 + n16) * INNER + quad * 8;
        bf16x8 aF0 = *(const bf16x8*)(qrow);
        bf16x8 aF1 = *(const bf16x8*)(qrow + 32);
        f32x4 acc[8];
        #pragma unroll
        for (int t = 0; t < 8; ++t) {
            acc[t] = __builtin_amdgcn_mfma_f32_16x16x32_bf16(aF0, bF[t][0], zero,   0, 0, 0);
            acc[t] = __builtin_amdgcn_mfma_f32_16x16x32_bf16(aF1, bF[t][1], acc[t], 0, 0, 0);
        }
        #pragma unroll
        for (int r = 0; r < 4; ++r) {
            float sv[8];
            float m = -3.0e38f;
            #pragma unroll
            for (int t = 0; t < 8; ++t) {
                sv[t] = acc[t][r] * 0.125f + am[t];
                m = fmaxf(m, sv[t]);
            }
            #pragma unroll
            for (int o = 1; o < 16; o <<= 1) m = fmaxf(m, __shfl_xor(m, o, 16));
            float l = 0.f, p = 0.f;
            #pragma unroll
            for (int t = 0; t < 8; ++t) {
                float e = __expf(sv[t] - m);
                l += e; p += e * vpv[t];
            }
            #pragma unroll
            for (int o = 1; o < 16; o <<= 1) {
                l += __shfl_xor(l, o, 16);
                p += __shfl_xor(p, o, 16);
            }
            if (n16 == 0)
                s_buf[((long long)(c * HEADS + h)) * N_SEQ + r0 + quad * 4 + r] = p / l;
        }
    }
}

// ---------------------------------------------------------------------------
// K8: final: pred[n,c] = softplus(e_dot[n] + sum_h s[c,h,n] + bop + bp)
// ---------------------------------------------------------------------------
__global__ void final_kernel(const float* __restrict__ s_buf,
                             const float* __restrict__ e_dot,
                             const float* __restrict__ bop,
                             const float* __restrict__ bp,
                             float* __restrict__ out) {
    int t = blockIdx.x * blockDim.x + threadIdx.x;
    if (t >= N_SEQ * NCTX) return;
    int n = t >> 6, c = t & 63;
    float s = 0.f;
    #pragma unroll
    for (int h = 0; h < HEADS; ++h) s += s_buf[((long long)(c * HEADS + h)) * N_SEQ + n];
    float x = e_dot[n] + s + *bop + *bp;
    out[t] = fmaxf(x, 0.f) + log1pf(__expf(-fabsf(x)));
}

// ---------------------------------------------------------------------------
extern "C" void kernel_launch(void* const* d_in, const int* in_sizes, int n_in,
                              void* d_out, int out_size, void* d_ws, size_t ws_size,
                              hipStream_t stream) {
    const float* emb   = (const float*)d_in[0];
    const float* ctx   = (const float*)d_in[1];
    const int*   cmask = (const int*)  d_in[2];
    const float* qg    = (const float*)d_in[3];
    const float* qb_   = (const float*)d_in[4];
    const float* kvg   = (const float*)d_in[5];
    const float* kvb   = (const float*)d_in[6];
    const float* Wq    = (const float*)d_in[7];
    const float* Wkv   = (const float*)d_in[8];
    const float* nullk = (const float*)d_in[9];
    const float* nullv = (const float*)d_in[10];
    const float* Wo    = (const float*)d_in[11];
    const float* bo    = (const float*)d_in[12];
    const float* Wp    = (const float*)d_in[13];
    const float* bp    = (const float*)d_in[14];
    float* out  = (float*)d_out;
    float* ws_f = (float*)d_ws;

    float*  EDOT   = ws_f + OFF_EDOT;
    __bf16* QBF    = (__bf16*)(ws_f + OFF_QBF);
    __bf16* KBF    = (__bf16*)(ws_f + OFF_KBF);
    float*  VPM    = ws_f + OFF_VPM;
    float*  VPNULL = ws_f + OFF_VPNULL;
    float*  WOP    = ws_f + OFF_WOP;
    float*  BOP    = ws_f + OFF_BOP;
    float*  SBUF   = ws_f + OFF_SBUF;
    __bf16* ANQ    = (__bf16*)(ws_f + OFF_ANQ);
    __bf16* ANKV   = (__bf16*)(ws_f + OFF_ANKV);
    __bf16* WQT    = (__bf16*)(ws_f + OFF_WQT);
    __bf16* WKT    = (__bf16*)(ws_f + OFF_WKT);
    __bf16* WVPT   = (__bf16*)(ws_f + OFF_WVPT);
    float*  QSL    = ws_f + OFF_QSL;

    ln_bf16_kernel<3><<<N_SEQ, 256, 0, stream>>>(emb, qg, qb_, Wp, ANQ, EDOT);
    ln_bf16_kernel<1><<<MKV, 256, 0, stream>>>(ctx, kvg, kvb, nullptr, ANKV, nullptr);
    transpose_bf16_kernel<<<dim3(DH / 32, INNER / 32), 256, 0, stream>>>(Wq, DH, INNER, WQT);
    transpose_bf16_kernel<<<dim3(DC / 32, INNER / 32), 256, 0, stream>>>(Wkv, DC, 2 * INNER, WKT);
    wop_kernel<<<INNER + 1, 256, 0, stream>>>(Wo, bo, Wp, WOP, BOP);
    wvp_kernel<<<33, 256, 0, stream>>>(Wkv, WOP, nullv, nullk, WVPT, VPNULL, KBF);
    proj_kernel<<<480, 256, 0, stream>>>(ANQ, WQT, ANKV, WKT, WVPT, QSL, KBF, VPM);
    qreduce_kernel<<<(N_SEQ * INNER) / 256, 256, 0, stream>>>(QSL, QBF);
    attn_mfma_kernel<<<NCTX * HEADS, 256, 0, stream>>>(QBF, KBF, VPM, VPNULL, cmask, SBUF);
    final_kernel<<<(N_SEQ * NCTX + 255) / 256, 256, 0, stream>>>(SBUF, EDOT, BOP, bp, out);
}